// Round 6
// baseline (3280.987 us; speedup 1.0000x reference)
//
#include <hip/hip_runtime.h>
#include <cstdint>
#include <cstddef>

// ---------------------------------------------------------------------------
//   x:[4096,1,30,30] -> conv1(32,3x3)+relu -> conv2(64,3x3)+relu -> maxpool2
//   -> flatten [4096,10816] -> MoE(top2, 8 experts, 10816->128) -> relu
//   -> MoE(top2, 8 experts, 128->10) -> log_softmax
//   outputs: logp[4096,10], gt_l1[4096,8], gt_l2[4096,8], loss[1]
// ---------------------------------------------------------------------------

// ws layout (bytes)
static const size_t OFF_HFLAT = 0;                                        // 177,209,344
static const size_t OFF_H2Q   = (size_t)4096 * 10816 * 4;                 // 4096*4*128*4 = 8,388,608
static const size_t OFF_ROWS  = OFF_H2Q + (size_t)4096 * 4 * 128 * 4;     // 8*4096*4
static const size_t OFF_GATES = OFF_ROWS + (size_t)8 * 4096 * 4;          // 8*4096*4
static const size_t OFF_SMALL = OFF_GATES + (size_t)8 * 4096 * 4;         // 40*4
// small: [0..7] cnt(int) | [8..15] imp1 | [16..23] load1 | [24..31] imp2 | [32..39] load2

// ---------------- fused conv1 -> conv2 -> maxpool ---------------------------
// grid (4096, 2): x=image, y=oc half (32 oc). block 256.
// tid = ct*64 + prl*8 + ocg. Thread tile: 4 oc x 2 pre-rows x {6,6,6,8} pre-cols.
// __launch_bounds__(256, 2): VGPR cap 256 ((256,4) clamps to 64 and spills).
// Round 4: VGPR=128, FETCH 105 MB, 2010 us. Round 5 post-mortem: residual
// ~350-430 MB spill STORES came from '#pragma unroll 2' on the icl loop --
// two iterations' row buffers live at once (2x30-40) + 64 acc > 128 cap.
// Scratch allocation is also what pinned occupancy at 2 blocks/CU.
// THIS ROUND: unroll 1 on icl loop + rolling 3-row buffer -> live set ~110
// -> zero scratch -> 4 blocks/CU. Stride back to 28 (round-5 pad attacked a
// 2-way conflict that m136 shows is free; it cost LDS and duration).
// RACE FIX (round 3): __syncthreads() after initial staging (acc init reads
// s_b2 staged by tid<32).
// Bands of 8 pooled rows starting {0,5} (rows 5..7 recomputed identically).
// Epilogue: pooled tile staged to LDS then coalesced dword copy-out.

template<int PC>
__device__ __forceinline__ void ld_row(float* r, const float* __restrict__ p)
{
    #pragma unroll
    for (int c = 0; c < PC; c += 2) {
        float2 t = *(const float2*)(p + c);
        r[c] = t.x; r[c + 1] = t.y;
    }
}

template<int TC>
__device__ __forceinline__ void fma_ky(float acc[4][2][8], const float* ra, const float* rb,
                                       const float* __restrict__ wk)
{
    #pragma unroll
    for (int kx = 0; kx < 3; ++kx) {
        float4 w = *(const float4*)(wk + kx * 36);
        #pragma unroll
        for (int c = 0; c < 2 * TC; ++c) {
            float ia = ra[c + kx], ib = rb[c + kx];
            acc[0][0][c] = fmaf(ia, w.x, acc[0][0][c]);
            acc[1][0][c] = fmaf(ia, w.y, acc[1][0][c]);
            acc[2][0][c] = fmaf(ia, w.z, acc[2][0][c]);
            acc[3][0][c] = fmaf(ia, w.w, acc[3][0][c]);
            acc[0][1][c] = fmaf(ib, w.x, acc[0][1][c]);
            acc[1][1][c] = fmaf(ib, w.y, acc[1][1][c]);
            acc[2][1][c] = fmaf(ib, w.z, acc[2][1][c]);
            acc[3][1][c] = fmaf(ib, w.w, acc[3][1][c]);
        }
    }
}

template<int TC>
__device__ __forceinline__ void conv2_accum(const float* __restrict__ hb,
                                            const float* __restrict__ wb,
                                            float acc[4][2][8])
{
    #pragma unroll 1
    for (int icl = 0; icl < 8; ++icl) {
        const float* h = hb + icl * 504;   // [icl][r][28] band
        const float* w = wb + icl * 324;   // [icl][kk 0..8][36]
        // rolling 3-row buffer: r0 reused for the 4th row (keeps live set low)
        float r0[2 * TC + 2], r1[2 * TC + 2], r2[2 * TC + 2];
        ld_row<2 * TC + 2>(r0, h);
        ld_row<2 * TC + 2>(r1, h + 28);
        fma_ky<TC>(acc, r0, r1, w);
        ld_row<2 * TC + 2>(r2, h + 56);
        fma_ky<TC>(acc, r1, r2, w + 108);
        ld_row<2 * TC + 2>(r0, h + 84);
        fma_ky<TC>(acc, r2, r0, w + 216);
    }
}

__global__ __launch_bounds__(256, 2)
void conv_fused(const float* __restrict__ x,
                const float* __restrict__ w1, const float* __restrict__ b1,
                const float* __restrict__ w2, const float* __restrict__ b2,
                float* __restrict__ hflat)
{
    __shared__ float s_in[900];
    __shared__ float s_w1[288];
    __shared__ float s_b1[32];
    __shared__ float s_b2[32];
    __shared__ float s_h1[4032];    // [icl(8)][r(18)][c(28)] band; reused as out stage [32][105]
    __shared__ float s_w2c[2592];   // [kk(72)=icl*9+k][oc pad36] for current ic-chunk

    const int img = blockIdx.x, oh = blockIdx.y, tid = threadIdx.x;

    const float* xin = x + (size_t)img * 900;
    for (int i = tid; i < 900; i += 256) s_in[i] = xin[i];
    for (int i = tid; i < 288; i += 256) s_w1[i] = w1[i];
    if (tid < 32) { s_b1[tid] = b1[tid]; s_b2[tid] = b2[oh * 32 + tid]; }
    __syncthreads();   // RACE FIX: acc init below reads s_b2 staged by tid<32

    const int ct  = tid >> 6;          // 0..3 (wave-uniform)
    const int prl = (tid >> 3) & 7;    // 0..7
    const int ocg = tid & 7;           // 0..7
    const int c0  = ct * 6;            // pre-col start: 0,6,12,18
    const int pc0 = ct * 3;            // pooled-col start
    const int TCp = (ct < 3) ? 3 : 4;  // pooled cols this thread

    const float* hb = s_h1 + 2 * prl * 28 + c0;
    const float* wb = s_w2c + ocg * 4;
    const float* w2g = w2 + (size_t)oh * 32 * 288;   // [oc(32)][ic*9+k]

    #pragma unroll 1
    for (int band = 0; band < 2; ++band) {
        const int rb = band * 5;                 // pooled rows rb..rb+7
        float acc[4][2][8];
        #pragma unroll
        for (int o = 0; o < 4; ++o) {
            float bb = s_b2[ocg * 4 + o];
            #pragma unroll
            for (int r = 0; r < 2; ++r)
                #pragma unroll
                for (int c = 0; c < 8; ++c) acc[o][r][c] = bb;
        }
        #pragma unroll 1
        for (int ch = 0; ch < 4; ++ch) {
            __syncthreads();   // previous compute/copy-out done before restaging
            // --- stage conv1: pre rows 2rb..2rb+17, ic chunk ch*8..+7 ---
            #pragma unroll
            for (int it = 0; it < 16; ++it) {
                int i2 = it * 256 + tid;
                if (i2 < 4032) {
                    int q = i2 / 28;           // icl*18 + r
                    int c = i2 - q * 28;
                    int icl = q / 18;
                    int r = q - icl * 18;
                    int ic = ch * 8 + icl;
                    int grow = 2 * rb + r;     // <= 27
                    const float* wp = &s_w1[ic * 9];
                    const float* ip = &s_in[grow * 30 + c];
                    float v = s_b1[ic];
                    v = fmaf(ip[0],  wp[0], v); v = fmaf(ip[1],  wp[1], v); v = fmaf(ip[2],  wp[2], v);
                    v = fmaf(ip[30], wp[3], v); v = fmaf(ip[31], wp[4], v); v = fmaf(ip[32], wp[5], v);
                    v = fmaf(ip[60], wp[6], v); v = fmaf(ip[61], wp[7], v); v = fmaf(ip[62], wp[8], v);
                    s_h1[i2] = fmaxf(v, 0.f);
                }
            }
            // --- stage conv2 weights for this ic chunk: [72][oc pad36] ---
            #pragma unroll
            for (int it = 0; it < 9; ++it) {
                int i = it * 256 + tid;        // 0..2303 exact
                int oc = i / 72;
                int r = i - oc * 72;
                s_w2c[r * 36 + oc] = w2g[oc * 288 + ch * 72 + r];
            }
            __syncthreads();
            if (ct < 3) conv2_accum<3>(hb, wb, acc);
            else        conv2_accum<4>(hb, wb, acc);
        }
        // --- pool 2x2 + relu -> LDS stage (reuse s_h1) ---
        __syncthreads();   // all conv2 reads of s_h1 done before overwrite
        float* s_out = s_h1;   // [32 oc][105] (13 cols x 8 rows + pad 1)
        #pragma unroll
        for (int o = 0; o < 4; ++o)
            #pragma unroll
            for (int c = 0; c < 4; ++c) {
                if (c < TCp) {
                    float m = fmaxf(fmaxf(acc[o][0][2 * c], acc[o][0][2 * c + 1]),
                                    fmaxf(acc[o][1][2 * c], acc[o][1][2 * c + 1]));
                    s_out[(ocg * 4 + o) * 105 + prl * 13 + pc0 + c] = fmaxf(m, 0.f);
                }
            }
        __syncthreads();
        // --- coalesced copy-out: 32 oc x 104 contiguous floats per channel ---
        // global: hflat[img][ (oh*32+oc)*169 + rb*13 + j ], j in [0,104)
        float* gbase = hflat + (size_t)img * 10816 + (size_t)oh * 32 * 169 + rb * 13;
        #pragma unroll
        for (int it = 0; it < 13; ++it) {
            int i = it * 256 + tid;            // 0..3327 exact (13*256 = 3328)
            int oc = i / 104;
            int j  = i - oc * 104;
            gbase[oc * 169 + j] = s_out[oc * 105 + j];
        }
    }
}

// ---------------- gate layer 1: logits, top-2, scatter to expert bins -------
__global__ __launch_bounds__(256)
void gate1_kernel(const float* __restrict__ hflat, const float* __restrict__ wg,
                  float* __restrict__ gt1,
                  int* __restrict__ rows_list, float* __restrict__ gate_list,
                  int* __restrict__ cnt, float* __restrict__ imp, float* __restrict__ load)
{
    __shared__ float s_imp[8], s_load[8];
    const int tid = threadIdx.x;
    if (tid < 8) { s_imp[tid] = 0.f; s_load[tid] = 0.f; }
    __syncthreads();
    const int wave = tid >> 6, lane = tid & 63;
    const int row = blockIdx.x * 4 + wave;
    const float* hp = hflat + (size_t)row * 10816;
    float acc[8] = {0.f, 0.f, 0.f, 0.f, 0.f, 0.f, 0.f, 0.f};
    for (int k0 = lane * 4; k0 < 10816; k0 += 256) {
        float4 h4 = *(const float4*)(hp + k0);
        const float4* w4 = (const float4*)(wg + (size_t)k0 * 8);
        float hv[4] = {h4.x, h4.y, h4.z, h4.w};
        #pragma unroll
        for (int j = 0; j < 4; j++) {
            float4 wa = w4[2 * j], wb = w4[2 * j + 1];
            acc[0] = fmaf(hv[j], wa.x, acc[0]); acc[1] = fmaf(hv[j], wa.y, acc[1]);
            acc[2] = fmaf(hv[j], wa.z, acc[2]); acc[3] = fmaf(hv[j], wa.w, acc[3]);
            acc[4] = fmaf(hv[j], wb.x, acc[4]); acc[5] = fmaf(hv[j], wb.y, acc[5]);
            acc[6] = fmaf(hv[j], wb.z, acc[6]); acc[7] = fmaf(hv[j], wb.w, acc[7]);
        }
    }
    #pragma unroll
    for (int e = 0; e < 8; e++)
        #pragma unroll
        for (int off = 32; off > 0; off >>= 1)
            acc[e] += __shfl_down(acc[e], off, 64);
    if (lane == 0) {
        int i0 = 0; float v0 = acc[0];
        #pragma unroll
        for (int e = 1; e < 8; e++) if (acc[e] > v0) { v0 = acc[e]; i0 = e; }
        int i1 = -1; float v1 = -1e30f;
        #pragma unroll
        for (int e = 0; e < 8; e++) if (e != i0 && acc[e] > v1) { v1 = acc[e]; i1 = e; }
        float ex = expf(v1 - v0);
        float g0 = 1.f / (1.f + ex);
        float g1 = ex / (1.f + ex);
        float* gp = gt1 + (size_t)row * 8;
        #pragma unroll
        for (int e = 0; e < 8; e++) gp[e] = 0.f;
        gp[i0] = g0; gp[i1] = g1;
        atomicAdd(&s_imp[i0], g0); atomicAdd(&s_imp[i1], g1);
        atomicAdd(&s_load[i0], 1.f); atomicAdd(&s_load[i1], 1.f);
        int p0 = atomicAdd(&cnt[i0], 1);
        rows_list[i0 * 4096 + p0] = row * 2 + 0; gate_list[i0 * 4096 + p0] = g0;
        int p1 = atomicAdd(&cnt[i1], 1);
        rows_list[i1 * 4096 + p1] = row * 2 + 1; gate_list[i1 * 4096 + p1] = g1;
    }
    __syncthreads();
    if (tid < 8) { atomicAdd(&imp[tid], s_imp[tid]); atomicAdd(&load[tid], s_load[tid]); }
}

// ---------------- MoE1 expert GEMM: M=64, N=128, K-split x2 -----------------
__global__ __launch_bounds__(256)
void moe1_gemm(const float* __restrict__ hflat, const float* __restrict__ W1,
               const float* __restrict__ b1g,
               const int* __restrict__ rows_list, const float* __restrict__ gate_list,
               const int* __restrict__ cnt, float* __restrict__ h2quad)
{
    const int e  = blockIdx.x;
    const int t  = blockIdx.y >> 1;
    const int kh = blockIdx.y & 1;
    const int n = cnt[e];
    if (t * 64 >= n) return;
    __shared__ float sA[32][68];     // [k][m] pad 68
    __shared__ float sB[32][132];    // [k][n] pad 132
    __shared__ int   s_rows[64];
    __shared__ float s_gate[64];
    const int tid = threadIdx.x;
    const int mr = (n - t * 64 < 64) ? (n - t * 64) : 64;
    if (tid < 64) {
        int idx = t * 64 + ((tid < mr) ? tid : 0);
        s_rows[tid] = rows_list[e * 4096 + idx];
        s_gate[tid] = (tid < mr) ? gate_list[e * 4096 + t * 64 + tid] : 0.f;
    }
    __syncthreads();
    float acc[8][4];
    #pragma unroll
    for (int i = 0; i < 8; i++)
        #pragma unroll
        for (int j = 0; j < 4; j++) acc[i][j] = 0.f;
    const int tm = tid >> 5;            // 0..7 -> rows tm*8..+7
    const int tn = tid & 31;            // cols tn*4..+3
    const float* Wb = W1 + (size_t)e * 10816 * 128;
    const int ar = tid >> 2;            // 0..63
    const int ak = (tid & 3) * 8;       // 0,8,16,24
    const int bk = tid >> 3;            // 0..31
    const int bn = (tid & 7) * 16;
    const int kbase = kh * 5408;
    const float* agp = hflat + (size_t)(s_rows[ar] >> 1) * 10816 + kbase;
    for (int k0 = 0; k0 < 5408; k0 += 32) {
        float4 a0 = *(const float4*)(agp + k0 + ak);
        float4 a1 = *(const float4*)(agp + k0 + ak + 4);
        const float4* bsrc = (const float4*)(Wb + (size_t)(kbase + k0 + bk) * 128 + bn);
        float4 b0 = bsrc[0], b1v = bsrc[1], b2v = bsrc[2], b3v = bsrc[3];
        __syncthreads();
        sA[ak + 0][ar] = a0.x; sA[ak + 1][ar] = a0.y; sA[ak + 2][ar] = a0.z; sA[ak + 3][ar] = a0.w;
        sA[ak + 4][ar] = a1.x; sA[ak + 5][ar] = a1.y; sA[ak + 6][ar] = a1.z; sA[ak + 7][ar] = a1.w;
        *(float4*)&sB[bk][bn + 0]  = b0; *(float4*)&sB[bk][bn + 4]  = b1v;
        *(float4*)&sB[bk][bn + 8]  = b2v; *(float4*)&sB[bk][bn + 12] = b3v;
        __syncthreads();
        #pragma unroll
        for (int k = 0; k < 32; k++) {
            float4 av0 = *(const float4*)&sA[k][tm * 8];
            float4 av1 = *(const float4*)&sA[k][tm * 8 + 4];
            float4 bv  = *(const float4*)&sB[k][tn * 4];
            acc[0][0] = fmaf(av0.x, bv.x, acc[0][0]); acc[0][1] = fmaf(av0.x, bv.y, acc[0][1]);
            acc[0][2] = fmaf(av0.x, bv.z, acc[0][2]); acc[0][3] = fmaf(av0.x, bv.w, acc[0][3]);
            acc[1][0] = fmaf(av0.y, bv.x, acc[1][0]); acc[1][1] = fmaf(av0.y, bv.y, acc[1][1]);
            acc[1][2] = fmaf(av0.y, bv.z, acc[1][2]); acc[1][3] = fmaf(av0.y, bv.w, acc[1][3]);
            acc[2][0] = fmaf(av0.z, bv.x, acc[2][0]); acc[2][1] = fmaf(av0.z, bv.y, acc[2][1]);
            acc[2][2] = fmaf(av0.z, bv.z, acc[2][2]); acc[2][3] = fmaf(av0.z, bv.w, acc[2][3]);
            acc[3][0] = fmaf(av0.w, bv.x, acc[3][0]); acc[3][1] = fmaf(av0.w, bv.y, acc[3][1]);
            acc[3][2] = fmaf(av0.w, bv.z, acc[3][2]); acc[3][3] = fmaf(av0.w, bv.w, acc[3][3]);
            acc[4][0] = fmaf(av1.x, bv.x, acc[4][0]); acc[4][1] = fmaf(av1.x, bv.y, acc[4][1]);
            acc[4][2] = fmaf(av1.x, bv.z, acc[4][2]); acc[4][3] = fmaf(av1.x, bv.w, acc[4][3]);
            acc[5][0] = fmaf(av1.y, bv.x, acc[5][0]); acc[5][1] = fmaf(av1.y, bv.y, acc[5][1]);
            acc[5][2] = fmaf(av1.y, bv.z, acc[5][2]); acc[5][3] = fmaf(av1.y, bv.w, acc[5][3]);
            acc[6][0] = fmaf(av1.z, bv.x, acc[6][0]); acc[6][1] = fmaf(av1.z, bv.y, acc[6][1]);
            acc[6][2] = fmaf(av1.z, bv.z, acc[6][2]); acc[6][3] = fmaf(av1.z, bv.w, acc[6][3]);
            acc[7][0] = fmaf(av1.w, bv.x, acc[7][0]); acc[7][1] = fmaf(av1.w, bv.y, acc[7][1]);
            acc[7][2] = fmaf(av1.w, bv.z, acc[7][2]); acc[7][3] = fmaf(av1.w, bv.w, acc[7][3]);
        }
    }
    const float* b1e = b1g + e * 128;
    float bx = (kh == 0) ? b1e[tn * 4 + 0] : 0.f;
    float by = (kh == 0) ? b1e[tn * 4 + 1] : 0.f;
    float bz = (kh == 0) ? b1e[tn * 4 + 2] : 0.f;
    float bw = (kh == 0) ? b1e[tn * 4 + 3] : 0.f;
    #pragma unroll
    for (int i = 0; i < 8; i++) {
        int m = tm * 8 + i;
        if (m < mr) {
            float g = s_gate[m];
            int rs = s_rows[m];
            float4 o;
            o.x = (acc[i][0] + bx) * g;
            o.y = (acc[i][1] + by) * g;
            o.z = (acc[i][2] + bz) * g;
            o.w = (acc[i][3] + bw) * g;
            *(float4*)(h2quad + ((size_t)rs * 2 + kh) * 128 + tn * 4) = o;
        }
    }
}

// ---------------- MoE2 head + log_softmax ----------------------------------
__global__ __launch_bounds__(64)
void moe2_head(const float* __restrict__ h2quad, const float* __restrict__ wg2,
               const float* __restrict__ W2, const float* __restrict__ b2,
               float* __restrict__ gt2, float* __restrict__ logp,
               float* __restrict__ imp2, float* __restrict__ load2)
{
    __shared__ float s_wg[128 * 8];
    __shared__ float s_W2[8 * 128 * 10];
    __shared__ float s_b2[80];
    __shared__ float s_imp[8], s_load[8];
    const int tid = threadIdx.x;
    for (int i = tid; i < 1024; i += 64) s_wg[i] = wg2[i];
    for (int i = tid; i < 10240; i += 64) s_W2[i] = W2[i];
    for (int i = tid; i < 80; i += 64) s_b2[i] = b2[i];
    if (tid < 8) { s_imp[tid] = 0.f; s_load[tid] = 0.f; }
    __syncthreads();
    const int row = blockIdx.x * 64 + tid;
    float h[128];
    const float* p0 = h2quad + (size_t)row * 512;
    #pragma unroll
    for (int i = 0; i < 128; i += 4) {
        float4 a = *(const float4*)(p0 + i);
        float4 b = *(const float4*)(p0 + 128 + i);
        float4 c = *(const float4*)(p0 + 256 + i);
        float4 d = *(const float4*)(p0 + 384 + i);
        h[i + 0] = fmaxf(a.x + b.x + c.x + d.x, 0.f);
        h[i + 1] = fmaxf(a.y + b.y + c.y + d.y, 0.f);
        h[i + 2] = fmaxf(a.z + b.z + c.z + d.z, 0.f);
        h[i + 3] = fmaxf(a.w + b.w + c.w + d.w, 0.f);
    }
    float lg[8] = {0.f, 0.f, 0.f, 0.f, 0.f, 0.f, 0.f, 0.f};
    #pragma unroll
    for (int k = 0; k < 128; k++) {
        float hv = h[k];
        #pragma unroll
        for (int e = 0; e < 8; e++) lg[e] = fmaf(hv, s_wg[k * 8 + e], lg[e]);
    }
    int i0 = 0; float v0 = lg[0];
    #pragma unroll
    for (int e = 1; e < 8; e++) if (lg[e] > v0) { v0 = lg[e]; i0 = e; }
    int i1 = -1; float v1 = -1e30f;
    #pragma unroll
    for (int e = 0; e < 8; e++) if (e != i0 && lg[e] > v1) { v1 = lg[e]; i1 = e; }
    float ex = expf(v1 - v0);
    float g0 = 1.f / (1.f + ex);
    float g1 = ex / (1.f + ex);
    float* gp = gt2 + (size_t)row * 8;
    #pragma unroll
    for (int e = 0; e < 8; e++) gp[e] = 0.f;
    gp[i0] = g0; gp[i1] = g1;
    atomicAdd(&s_imp[i0], g0); atomicAdd(&s_imp[i1], g1);
    atomicAdd(&s_load[i0], 1.f); atomicAdd(&s_load[i1], 1.f);
    float y[10];
    #pragma unroll
    for (int nn = 0; nn < 10; nn++)
        y[nn] = g0 * s_b2[i0 * 10 + nn] + g1 * s_b2[i1 * 10 + nn];
    #pragma unroll
    for (int k = 0; k < 128; k++) {
        float a = g0 * h[k];
        float b = g1 * h[k];
        const float* w0p = &s_W2[(i0 * 128 + k) * 10];
        const float* w1p = &s_W2[(i1 * 128 + k) * 10];
        #pragma unroll
        for (int nn = 0; nn < 10; nn++)
            y[nn] = fmaf(a, w0p[nn], fmaf(b, w1p[nn], y[nn]));
    }
    float m = y[0];
    #pragma unroll
    for (int nn = 1; nn < 10; nn++) m = fmaxf(m, y[nn]);
    float s = 0.f;
    #pragma unroll
    for (int nn = 0; nn < 10; nn++) s += expf(y[nn] - m);
    float ls = m + logf(s);
    float* op = logp + (size_t)row * 10;
    #pragma unroll
    for (int nn = 0; nn < 10; nn++) op[nn] = y[nn] - ls;
    __syncthreads();
    if (tid < 8) { atomicAdd(&imp2[tid], s_imp[tid]); atomicAdd(&load2[tid], s_load[tid]); }
}

// ---------------- loss ------------------------------------------------------
__device__ float cv_sq(const float* v)
{
    float m = 0.f;
    for (int i = 0; i < 8; i++) m += v[i];
    m *= 0.125f;
    float s = 0.f;
    for (int i = 0; i < 8; i++) { float d = v[i] - m; s += d * d; }
    float var = s * (1.f / 7.f);          // ddof=1
    return var / (m * m + 1e-10f);
}

__global__ void loss_kernel(const float* __restrict__ imp1, const float* __restrict__ load1,
                            const float* __restrict__ imp2, const float* __restrict__ load2,
                            float* __restrict__ out)
{
    if (threadIdx.x == 0) {
        float l = (cv_sq(imp1) + cv_sq(load1) + cv_sq(imp2) + cv_sq(load2)) * 3e-5f;
        out[0] = l;
    }
}

// ---------------------------------------------------------------------------
extern "C" void kernel_launch(void* const* d_in, const int* in_sizes, int n_in,
                              void* d_out, int out_size, void* d_ws, size_t ws_size,
                              hipStream_t stream)
{
    const float* x       = (const float*)d_in[0];
    const float* conv1_w = (const float*)d_in[1];
    const float* conv1_b = (const float*)d_in[2];
    const float* conv2_w = (const float*)d_in[3];
    const float* conv2_b = (const float*)d_in[4];
    const float* w_gate1 = (const float*)d_in[5];
    const float* W1      = (const float*)d_in[6];
    const float* b1      = (const float*)d_in[7];
    const float* w_gate2 = (const float*)d_in[8];
    const float* W2      = (const float*)d_in[9];
    const float* b2      = (const float*)d_in[10];

    char* ws = (char*)d_ws;
    float* h_flat    = (float*)(ws + OFF_HFLAT);
    float* h2quad    = (float*)(ws + OFF_H2Q);
    int*   rows_list = (int*)  (ws + OFF_ROWS);
    float* gate_list = (float*)(ws + OFF_GATES);
    int*   cnt1      = (int*)  (ws + OFF_SMALL);
    float* imp1      = (float*)(ws + OFF_SMALL) + 8;
    float* load1     = (float*)(ws + OFF_SMALL) + 16;
    float* imp2      = (float*)(ws + OFF_SMALL) + 24;
    float* load2     = (float*)(ws + OFF_SMALL) + 32;

    float* logp_out = (float*)d_out;            // [4096,10]
    float* gt1_out  = (float*)d_out + 40960;    // [4096,8]
    float* gt2_out  = (float*)d_out + 73728;    // [4096,8]
    float* loss_out = (float*)d_out + 106496;   // [1]

    hipMemsetAsync(ws + OFF_SMALL, 0, 40 * sizeof(float), stream);

    conv_fused<<<dim3(4096, 2), 256, 0, stream>>>(x, conv1_w, conv1_b, conv2_w, conv2_b, h_flat);
    gate1_kernel<<<1024, 256, 0, stream>>>(h_flat, w_gate1, gt1_out,
                                           rows_list, gate_list, cnt1, imp1, load1);
    moe1_gemm<<<dim3(8, 128), 256, 0, stream>>>(h_flat, W1, b1, rows_list, gate_list,
                                                cnt1, h2quad);
    moe2_head<<<64, 64, 0, stream>>>(h2quad, w_gate2, W2, b2,
                                     gt2_out, logp_out, imp2, load2);
    loss_kernel<<<1, 64, 0, stream>>>(imp1, load1, imp2, load2, loss_out);
}

// Round 7
// 2992.809 us; speedup vs baseline: 1.0963x; 1.0963x over previous
//
#include <hip/hip_runtime.h>
#include <cstdint>
#include <cstddef>

// ---------------------------------------------------------------------------
//   x:[4096,1,30,30] -> conv1(32,3x3)+relu -> conv2(64,3x3)+relu -> maxpool2
//   -> flatten [4096,10816] -> MoE(top2, 8 experts, 10816->128) -> relu
//   -> MoE(top2, 8 experts, 128->10) -> log_softmax
//   outputs: logp[4096,10], gt_l1[4096,8], gt_l2[4096,8], loss[1]
// ---------------------------------------------------------------------------

// ws layout (bytes)
static const size_t OFF_HFLAT = 0;                                        // 177,209,344
static const size_t OFF_H2Q   = (size_t)4096 * 10816 * 4;                 // 4096*4*128*4 = 8,388,608
static const size_t OFF_ROWS  = OFF_H2Q + (size_t)4096 * 4 * 128 * 4;     // 8*4096*4
static const size_t OFF_GATES = OFF_ROWS + (size_t)8 * 4096 * 4;          // 8*4096*4
static const size_t OFF_SMALL = OFF_GATES + (size_t)8 * 4096 * 4;         // 40*4
// small: [0..7] cnt(int) | [8..15] imp1 | [16..23] load1 | [24..31] imp2 | [32..39] load2

// ---------------- fused conv1 -> conv2 -> maxpool ---------------------------
// ROUND 7 RESTRUCTURE: one 512-thread block per image (grid 4096), all 64 oc.
// Rounds 4-6 showed the ~400 MB excess WRITE + ~120 MB excess FETCH were the
// hflat write path: per-oc 416-B runs at 676-B stride, split across bands ->
// partial-line fetch-on-write (2x128B per run ~ 134 MB = measured FETCH) and
// double eviction of boundary lines (~2-3x writeback). Fix: stage the whole
// image's pooled output in LDS (s_out[10816]) and copy out ONCE, dense and
// 128-aligned (43264 B/image = 338 full lines). Bonus: conv1 staging, x load,
// and w2 staging now done once per image instead of twice (oh halves merged).
// tid = ct*128 + prl*16 + ocg. Thread tile: 4 oc x 2 pre-rows x {6,6,6,8}
// pre-cols (identical per-thread work to round 4's best variant).
// LDS ~84 KB -> 1 block/CU (8 waves resident, same as before's 2x4 waves).
// __launch_bounds__(512, 2): VGPR cap 256 (same as round 4; (x,4+) clamps to
// 64 and spills multi-GB -- rounds 0-2 lesson).
// RACE FIX (round 3): __syncthreads() after initial staging (acc init reads
// s_b2 staged by tid<64).
// Bands of 8 pooled rows starting {0,5} (rows 5..7 recomputed identically).

template<int PC>
__device__ __forceinline__ void ld_row(float* r, const float* __restrict__ p)
{
    #pragma unroll
    for (int c = 0; c < PC; c += 2) {
        float2 t = *(const float2*)(p + c);
        r[c] = t.x; r[c + 1] = t.y;
    }
}

template<int TC>
__device__ __forceinline__ void fma_ky(float acc[4][2][8], const float* ra, const float* rb,
                                       const float* __restrict__ wk)
{
    #pragma unroll
    for (int kx = 0; kx < 3; ++kx) {
        float4 w = *(const float4*)(wk + kx * 68);   // [kk][oc pad68]
        #pragma unroll
        for (int c = 0; c < 2 * TC; ++c) {
            float ia = ra[c + kx], ib = rb[c + kx];
            acc[0][0][c] = fmaf(ia, w.x, acc[0][0][c]);
            acc[1][0][c] = fmaf(ia, w.y, acc[1][0][c]);
            acc[2][0][c] = fmaf(ia, w.z, acc[2][0][c]);
            acc[3][0][c] = fmaf(ia, w.w, acc[3][0][c]);
            acc[0][1][c] = fmaf(ib, w.x, acc[0][1][c]);
            acc[1][1][c] = fmaf(ib, w.y, acc[1][1][c]);
            acc[2][1][c] = fmaf(ib, w.z, acc[2][1][c]);
            acc[3][1][c] = fmaf(ib, w.w, acc[3][1][c]);
        }
    }
}

template<int TC>
__device__ __forceinline__ void conv2_accum(const float* __restrict__ hb,
                                            const float* __restrict__ wb,
                                            float acc[4][2][8])
{
    #pragma unroll 2
    for (int icl = 0; icl < 8; ++icl) {
        const float* h = hb + icl * 504;   // [icl][r][28] band
        const float* w = wb + icl * 612;   // [icl][kk 0..8][68]
        float r0[2 * TC + 2], r1[2 * TC + 2], r2[2 * TC + 2], r3[2 * TC + 2];
        ld_row<2 * TC + 2>(r0, h);
        ld_row<2 * TC + 2>(r1, h + 28);
        fma_ky<TC>(acc, r0, r1, w);
        ld_row<2 * TC + 2>(r2, h + 56);
        fma_ky<TC>(acc, r1, r2, w + 204);
        ld_row<2 * TC + 2>(r3, h + 84);
        fma_ky<TC>(acc, r2, r3, w + 408);
    }
}

__global__ __launch_bounds__(512, 2)
void conv_fused(const float* __restrict__ x,
                const float* __restrict__ w1, const float* __restrict__ b1,
                const float* __restrict__ w2, const float* __restrict__ b2,
                float* __restrict__ hflat)
{
    __shared__ float s_in[900];
    __shared__ float s_w1[288];
    __shared__ float s_b1[32];
    __shared__ float s_b2[64];
    __shared__ float s_h1[4032];     // [icl(8)][r(18)][c(28)] band
    __shared__ float s_w2c[4896];    // [kk(72)=icl*9+k][oc(64) pad68] current ic-chunk
    __shared__ float s_out[10816];   // full pooled image [64 oc][13][13]

    const int img = blockIdx.x, tid = threadIdx.x;

    const float* xin = x + (size_t)img * 900;
    for (int i = tid; i < 900; i += 512) s_in[i] = xin[i];
    if (tid < 288) s_w1[tid] = w1[tid];
    if (tid < 32) s_b1[tid] = b1[tid];
    if (tid < 64) s_b2[tid] = b2[tid];
    __syncthreads();   // RACE FIX: acc init below reads s_b2

    const int ct  = tid >> 7;          // 0..3 (wave-uniform: 2 waves per ct)
    const int prl = (tid >> 4) & 7;    // 0..7
    const int ocg = tid & 15;          // 0..15 -> oc ocg*4..+3
    const int c0  = ct * 6;            // pre-col start: 0,6,12,18
    const int pc0 = ct * 3;            // pooled-col start
    const int TCp = (ct < 3) ? 3 : 4;  // pooled cols this thread

    const float* hb = s_h1 + 2 * prl * 28 + c0;
    const float* wb = s_w2c + ocg * 4;

    #pragma unroll 1
    for (int band = 0; band < 2; ++band) {
        const int rb = band * 5;                 // pooled rows rb..rb+7
        float acc[4][2][8];
        #pragma unroll
        for (int o = 0; o < 4; ++o) {
            float bb = s_b2[ocg * 4 + o];
            #pragma unroll
            for (int r = 0; r < 2; ++r)
                #pragma unroll
                for (int c = 0; c < 8; ++c) acc[o][r][c] = bb;
        }
        #pragma unroll 1
        for (int ch = 0; ch < 4; ++ch) {
            __syncthreads();   // previous compute done before restaging s_h1/s_w2c
            // --- stage conv1: pre rows 2rb..2rb+17, ic chunk ch*8..+7 ---
            #pragma unroll
            for (int it = 0; it < 8; ++it) {
                int i2 = it * 512 + tid;
                if (i2 < 4032) {
                    int q = i2 / 28;           // icl*18 + r
                    int c = i2 - q * 28;
                    int icl = q / 18;
                    int r = q - icl * 18;
                    int ic = ch * 8 + icl;
                    int grow = 2 * rb + r;     // <= 27
                    const float* wp = &s_w1[ic * 9];
                    const float* ip = &s_in[grow * 30 + c];
                    float v = s_b1[ic];
                    v = fmaf(ip[0],  wp[0], v); v = fmaf(ip[1],  wp[1], v); v = fmaf(ip[2],  wp[2], v);
                    v = fmaf(ip[30], wp[3], v); v = fmaf(ip[31], wp[4], v); v = fmaf(ip[32], wp[5], v);
                    v = fmaf(ip[60], wp[6], v); v = fmaf(ip[61], wp[7], v); v = fmaf(ip[62], wp[8], v);
                    s_h1[i2] = fmaxf(v, 0.f);
                }
            }
            // --- stage conv2 weights: [72][oc(64) pad68] for this ic chunk ---
            #pragma unroll
            for (int it = 0; it < 9; ++it) {
                int i = it * 512 + tid;        // 0..4607 exact (9*512 = 4608 = 64*72)
                int oc = i / 72;
                int r = i - oc * 72;
                s_w2c[r * 68 + oc] = w2[oc * 288 + ch * 72 + r];
            }
            __syncthreads();
            if (ct < 3) conv2_accum<3>(hb, wb, acc);
            else        conv2_accum<4>(hb, wb, acc);
        }
        // --- pool 2x2 + relu -> s_out (separate array; no sync needed:
        //     next band's ch=0 __syncthreads covers the s_h1 reuse) ---
        #pragma unroll
        for (int o = 0; o < 4; ++o)
            #pragma unroll
            for (int c = 0; c < 4; ++c) {
                if (c < TCp) {
                    float m = fmaxf(fmaxf(acc[o][0][2 * c], acc[o][0][2 * c + 1]),
                                    fmaxf(acc[o][1][2 * c], acc[o][1][2 * c + 1]));
                    s_out[(ocg * 4 + o) * 169 + (rb + prl) * 13 + pc0 + c] = fmaxf(m, 0.f);
                }
            }
    }
    __syncthreads();   // s_out complete
    // --- single dense aligned copy-out: 10816 floats, base 128-aligned ---
    float* gbase = hflat + (size_t)img * 10816;
    #pragma unroll
    for (int it = 0; it < 22; ++it) {
        int i = it * 512 + tid;
        if (i < 10816) gbase[i] = s_out[i];
    }
}

// ---------------- gate layer 1: logits, top-2, scatter to expert bins -------
__global__ __launch_bounds__(256)
void gate1_kernel(const float* __restrict__ hflat, const float* __restrict__ wg,
                  float* __restrict__ gt1,
                  int* __restrict__ rows_list, float* __restrict__ gate_list,
                  int* __restrict__ cnt, float* __restrict__ imp, float* __restrict__ load)
{
    __shared__ float s_imp[8], s_load[8];
    const int tid = threadIdx.x;
    if (tid < 8) { s_imp[tid] = 0.f; s_load[tid] = 0.f; }
    __syncthreads();
    const int wave = tid >> 6, lane = tid & 63;
    const int row = blockIdx.x * 4 + wave;
    const float* hp = hflat + (size_t)row * 10816;
    float acc[8] = {0.f, 0.f, 0.f, 0.f, 0.f, 0.f, 0.f, 0.f};
    for (int k0 = lane * 4; k0 < 10816; k0 += 256) {
        float4 h4 = *(const float4*)(hp + k0);
        const float4* w4 = (const float4*)(wg + (size_t)k0 * 8);
        float hv[4] = {h4.x, h4.y, h4.z, h4.w};
        #pragma unroll
        for (int j = 0; j < 4; j++) {
            float4 wa = w4[2 * j], wb = w4[2 * j + 1];
            acc[0] = fmaf(hv[j], wa.x, acc[0]); acc[1] = fmaf(hv[j], wa.y, acc[1]);
            acc[2] = fmaf(hv[j], wa.z, acc[2]); acc[3] = fmaf(hv[j], wa.w, acc[3]);
            acc[4] = fmaf(hv[j], wb.x, acc[4]); acc[5] = fmaf(hv[j], wb.y, acc[5]);
            acc[6] = fmaf(hv[j], wb.z, acc[6]); acc[7] = fmaf(hv[j], wb.w, acc[7]);
        }
    }
    #pragma unroll
    for (int e = 0; e < 8; e++)
        #pragma unroll
        for (int off = 32; off > 0; off >>= 1)
            acc[e] += __shfl_down(acc[e], off, 64);
    if (lane == 0) {
        int i0 = 0; float v0 = acc[0];
        #pragma unroll
        for (int e = 1; e < 8; e++) if (acc[e] > v0) { v0 = acc[e]; i0 = e; }
        int i1 = -1; float v1 = -1e30f;
        #pragma unroll
        for (int e = 0; e < 8; e++) if (e != i0 && acc[e] > v1) { v1 = acc[e]; i1 = e; }
        float ex = expf(v1 - v0);
        float g0 = 1.f / (1.f + ex);
        float g1 = ex / (1.f + ex);
        float* gp = gt1 + (size_t)row * 8;
        #pragma unroll
        for (int e = 0; e < 8; e++) gp[e] = 0.f;
        gp[i0] = g0; gp[i1] = g1;
        atomicAdd(&s_imp[i0], g0); atomicAdd(&s_imp[i1], g1);
        atomicAdd(&s_load[i0], 1.f); atomicAdd(&s_load[i1], 1.f);
        int p0 = atomicAdd(&cnt[i0], 1);
        rows_list[i0 * 4096 + p0] = row * 2 + 0; gate_list[i0 * 4096 + p0] = g0;
        int p1 = atomicAdd(&cnt[i1], 1);
        rows_list[i1 * 4096 + p1] = row * 2 + 1; gate_list[i1 * 4096 + p1] = g1;
    }
    __syncthreads();
    if (tid < 8) { atomicAdd(&imp[tid], s_imp[tid]); atomicAdd(&load[tid], s_load[tid]); }
}

// ---------------- MoE1 expert GEMM: M=64, N=128, K-split x2 -----------------
__global__ __launch_bounds__(256)
void moe1_gemm(const float* __restrict__ hflat, const float* __restrict__ W1,
               const float* __restrict__ b1g,
               const int* __restrict__ rows_list, const float* __restrict__ gate_list,
               const int* __restrict__ cnt, float* __restrict__ h2quad)
{
    const int e  = blockIdx.x;
    const int t  = blockIdx.y >> 1;
    const int kh = blockIdx.y & 1;
    const int n = cnt[e];
    if (t * 64 >= n) return;
    __shared__ float sA[32][68];     // [k][m] pad 68
    __shared__ float sB[32][132];    // [k][n] pad 132
    __shared__ int   s_rows[64];
    __shared__ float s_gate[64];
    const int tid = threadIdx.x;
    const int mr = (n - t * 64 < 64) ? (n - t * 64) : 64;
    if (tid < 64) {
        int idx = t * 64 + ((tid < mr) ? tid : 0);
        s_rows[tid] = rows_list[e * 4096 + idx];
        s_gate[tid] = (tid < mr) ? gate_list[e * 4096 + t * 64 + tid] : 0.f;
    }
    __syncthreads();
    float acc[8][4];
    #pragma unroll
    for (int i = 0; i < 8; i++)
        #pragma unroll
        for (int j = 0; j < 4; j++) acc[i][j] = 0.f;
    const int tm = tid >> 5;            // 0..7 -> rows tm*8..+7
    const int tn = tid & 31;            // cols tn*4..+3
    const float* Wb = W1 + (size_t)e * 10816 * 128;
    const int ar = tid >> 2;            // 0..63
    const int ak = (tid & 3) * 8;       // 0,8,16,24
    const int bk = tid >> 3;            // 0..31
    const int bn = (tid & 7) * 16;
    const int kbase = kh * 5408;
    const float* agp = hflat + (size_t)(s_rows[ar] >> 1) * 10816 + kbase;
    for (int k0 = 0; k0 < 5408; k0 += 32) {
        float4 a0 = *(const float4*)(agp + k0 + ak);
        float4 a1 = *(const float4*)(agp + k0 + ak + 4);
        const float4* bsrc = (const float4*)(Wb + (size_t)(kbase + k0 + bk) * 128 + bn);
        float4 b0 = bsrc[0], b1v = bsrc[1], b2v = bsrc[2], b3v = bsrc[3];
        __syncthreads();
        sA[ak + 0][ar] = a0.x; sA[ak + 1][ar] = a0.y; sA[ak + 2][ar] = a0.z; sA[ak + 3][ar] = a0.w;
        sA[ak + 4][ar] = a1.x; sA[ak + 5][ar] = a1.y; sA[ak + 6][ar] = a1.z; sA[ak + 7][ar] = a1.w;
        *(float4*)&sB[bk][bn + 0]  = b0; *(float4*)&sB[bk][bn + 4]  = b1v;
        *(float4*)&sB[bk][bn + 8]  = b2v; *(float4*)&sB[bk][bn + 12] = b3v;
        __syncthreads();
        #pragma unroll
        for (int k = 0; k < 32; k++) {
            float4 av0 = *(const float4*)&sA[k][tm * 8];
            float4 av1 = *(const float4*)&sA[k][tm * 8 + 4];
            float4 bv  = *(const float4*)&sB[k][tn * 4];
            acc[0][0] = fmaf(av0.x, bv.x, acc[0][0]); acc[0][1] = fmaf(av0.x, bv.y, acc[0][1]);
            acc[0][2] = fmaf(av0.x, bv.z, acc[0][2]); acc[0][3] = fmaf(av0.x, bv.w, acc[0][3]);
            acc[1][0] = fmaf(av0.y, bv.x, acc[1][0]); acc[1][1] = fmaf(av0.y, bv.y, acc[1][1]);
            acc[1][2] = fmaf(av0.y, bv.z, acc[1][2]); acc[1][3] = fmaf(av0.y, bv.w, acc[1][3]);
            acc[2][0] = fmaf(av0.z, bv.x, acc[2][0]); acc[2][1] = fmaf(av0.z, bv.y, acc[2][1]);
            acc[2][2] = fmaf(av0.z, bv.z, acc[2][2]); acc[2][3] = fmaf(av0.z, bv.w, acc[2][3]);
            acc[3][0] = fmaf(av0.w, bv.x, acc[3][0]); acc[3][1] = fmaf(av0.w, bv.y, acc[3][1]);
            acc[3][2] = fmaf(av0.w, bv.z, acc[3][2]); acc[3][3] = fmaf(av0.w, bv.w, acc[3][3]);
            acc[4][0] = fmaf(av1.x, bv.x, acc[4][0]); acc[4][1] = fmaf(av1.x, bv.y, acc[4][1]);
            acc[4][2] = fmaf(av1.x, bv.z, acc[4][2]); acc[4][3] = fmaf(av1.x, bv.w, acc[4][3]);
            acc[5][0] = fmaf(av1.y, bv.x, acc[5][0]); acc[5][1] = fmaf(av1.y, bv.y, acc[5][1]);
            acc[5][2] = fmaf(av1.y, bv.z, acc[5][2]); acc[5][3] = fmaf(av1.y, bv.w, acc[5][3]);
            acc[6][0] = fmaf(av1.z, bv.x, acc[6][0]); acc[6][1] = fmaf(av1.z, bv.y, acc[6][1]);
            acc[6][2] = fmaf(av1.z, bv.z, acc[6][2]); acc[6][3] = fmaf(av1.z, bv.w, acc[6][3]);
            acc[7][0] = fmaf(av1.w, bv.x, acc[7][0]); acc[7][1] = fmaf(av1.w, bv.y, acc[7][1]);
            acc[7][2] = fmaf(av1.w, bv.z, acc[7][2]); acc[7][3] = fmaf(av1.w, bv.w, acc[7][3]);
        }
    }
    const float* b1e = b1g + e * 128;
    float bx = (kh == 0) ? b1e[tn * 4 + 0] : 0.f;
    float by = (kh == 0) ? b1e[tn * 4 + 1] : 0.f;
    float bz = (kh == 0) ? b1e[tn * 4 + 2] : 0.f;
    float bw = (kh == 0) ? b1e[tn * 4 + 3] : 0.f;
    #pragma unroll
    for (int i = 0; i < 8; i++) {
        int m = tm * 8 + i;
        if (m < mr) {
            float g = s_gate[m];
            int rs = s_rows[m];
            float4 o;
            o.x = (acc[i][0] + bx) * g;
            o.y = (acc[i][1] + by) * g;
            o.z = (acc[i][2] + bz) * g;
            o.w = (acc[i][3] + bw) * g;
            *(float4*)(h2quad + ((size_t)rs * 2 + kh) * 128 + tn * 4) = o;
        }
    }
}

// ---------------- MoE2 head + log_softmax ----------------------------------
__global__ __launch_bounds__(64)
void moe2_head(const float* __restrict__ h2quad, const float* __restrict__ wg2,
               const float* __restrict__ W2, const float* __restrict__ b2,
               float* __restrict__ gt2, float* __restrict__ logp,
               float* __restrict__ imp2, float* __restrict__ load2)
{
    __shared__ float s_wg[128 * 8];
    __shared__ float s_W2[8 * 128 * 10];
    __shared__ float s_b2[80];
    __shared__ float s_imp[8], s_load[8];
    const int tid = threadIdx.x;
    for (int i = tid; i < 1024; i += 64) s_wg[i] = wg2[i];
    for (int i = tid; i < 10240; i += 64) s_W2[i] = W2[i];
    for (int i = tid; i < 80; i += 64) s_b2[i] = b2[i];
    if (tid < 8) { s_imp[tid] = 0.f; s_load[tid] = 0.f; }
    __syncthreads();
    const int row = blockIdx.x * 64 + tid;
    float h[128];
    const float* p0 = h2quad + (size_t)row * 512;
    #pragma unroll
    for (int i = 0; i < 128; i += 4) {
        float4 a = *(const float4*)(p0 + i);
        float4 b = *(const float4*)(p0 + 128 + i);
        float4 c = *(const float4*)(p0 + 256 + i);
        float4 d = *(const float4*)(p0 + 384 + i);
        h[i + 0] = fmaxf(a.x + b.x + c.x + d.x, 0.f);
        h[i + 1] = fmaxf(a.y + b.y + c.y + d.y, 0.f);
        h[i + 2] = fmaxf(a.z + b.z + c.z + d.z, 0.f);
        h[i + 3] = fmaxf(a.w + b.w + c.w + d.w, 0.f);
    }
    float lg[8] = {0.f, 0.f, 0.f, 0.f, 0.f, 0.f, 0.f, 0.f};
    #pragma unroll
    for (int k = 0; k < 128; k++) {
        float hv = h[k];
        #pragma unroll
        for (int e = 0; e < 8; e++) lg[e] = fmaf(hv, s_wg[k * 8 + e], lg[e]);
    }
    int i0 = 0; float v0 = lg[0];
    #pragma unroll
    for (int e = 1; e < 8; e++) if (lg[e] > v0) { v0 = lg[e]; i0 = e; }
    int i1 = -1; float v1 = -1e30f;
    #pragma unroll
    for (int e = 0; e < 8; e++) if (e != i0 && lg[e] > v1) { v1 = lg[e]; i1 = e; }
    float ex = expf(v1 - v0);
    float g0 = 1.f / (1.f + ex);
    float g1 = ex / (1.f + ex);
    float* gp = gt2 + (size_t)row * 8;
    #pragma unroll
    for (int e = 0; e < 8; e++) gp[e] = 0.f;
    gp[i0] = g0; gp[i1] = g1;
    atomicAdd(&s_imp[i0], g0); atomicAdd(&s_imp[i1], g1);
    atomicAdd(&s_load[i0], 1.f); atomicAdd(&s_load[i1], 1.f);
    float y[10];
    #pragma unroll
    for (int nn = 0; nn < 10; nn++)
        y[nn] = g0 * s_b2[i0 * 10 + nn] + g1 * s_b2[i1 * 10 + nn];
    #pragma unroll
    for (int k = 0; k < 128; k++) {
        float a = g0 * h[k];
        float b = g1 * h[k];
        const float* w0p = &s_W2[(i0 * 128 + k) * 10];
        const float* w1p = &s_W2[(i1 * 128 + k) * 10];
        #pragma unroll
        for (int nn = 0; nn < 10; nn++)
            y[nn] = fmaf(a, w0p[nn], fmaf(b, w1p[nn], y[nn]));
    }
    float m = y[0];
    #pragma unroll
    for (int nn = 1; nn < 10; nn++) m = fmaxf(m, y[nn]);
    float s = 0.f;
    #pragma unroll
    for (int nn = 0; nn < 10; nn++) s += expf(y[nn] - m);
    float ls = m + logf(s);
    float* op = logp + (size_t)row * 10;
    #pragma unroll
    for (int nn = 0; nn < 10; nn++) op[nn] = y[nn] - ls;
    __syncthreads();
    if (tid < 8) { atomicAdd(&imp2[tid], s_imp[tid]); atomicAdd(&load2[tid], s_load[tid]); }
}

// ---------------- loss ------------------------------------------------------
__device__ float cv_sq(const float* v)
{
    float m = 0.f;
    for (int i = 0; i < 8; i++) m += v[i];
    m *= 0.125f;
    float s = 0.f;
    for (int i = 0; i < 8; i++) { float d = v[i] - m; s += d * d; }
    float var = s * (1.f / 7.f);          // ddof=1
    return var / (m * m + 1e-10f);
}

__global__ void loss_kernel(const float* __restrict__ imp1, const float* __restrict__ load1,
                            const float* __restrict__ imp2, const float* __restrict__ load2,
                            float* __restrict__ out)
{
    if (threadIdx.x == 0) {
        float l = (cv_sq(imp1) + cv_sq(load1) + cv_sq(imp2) + cv_sq(load2)) * 3e-5f;
        out[0] = l;
    }
}

// ---------------------------------------------------------------------------
extern "C" void kernel_launch(void* const* d_in, const int* in_sizes, int n_in,
                              void* d_out, int out_size, void* d_ws, size_t ws_size,
                              hipStream_t stream)
{
    const float* x       = (const float*)d_in[0];
    const float* conv1_w = (const float*)d_in[1];
    const float* conv1_b = (const float*)d_in[2];
    const float* conv2_w = (const float*)d_in[3];
    const float* conv2_b = (const float*)d_in[4];
    const float* w_gate1 = (const float*)d_in[5];
    const float* W1      = (const float*)d_in[6];
    const float* b1      = (const float*)d_in[7];
    const float* w_gate2 = (const float*)d_in[8];
    const float* W2      = (const float*)d_in[9];
    const float* b2      = (const float*)d_in[10];

    char* ws = (char*)d_ws;
    float* h_flat    = (float*)(ws + OFF_HFLAT);
    float* h2quad    = (float*)(ws + OFF_H2Q);
    int*   rows_list = (int*)  (ws + OFF_ROWS);
    float* gate_list = (float*)(ws + OFF_GATES);
    int*   cnt1      = (int*)  (ws + OFF_SMALL);
    float* imp1      = (float*)(ws + OFF_SMALL) + 8;
    float* load1     = (float*)(ws + OFF_SMALL) + 16;
    float* imp2      = (float*)(ws + OFF_SMALL) + 24;
    float* load2     = (float*)(ws + OFF_SMALL) + 32;

    float* logp_out = (float*)d_out;            // [4096,10]
    float* gt1_out  = (float*)d_out + 40960;    // [4096,8]
    float* gt2_out  = (float*)d_out + 73728;    // [4096,8]
    float* loss_out = (float*)d_out + 106496;   // [1]

    hipMemsetAsync(ws + OFF_SMALL, 0, 40 * sizeof(float), stream);

    conv_fused<<<4096, 512, 0, stream>>>(x, conv1_w, conv1_b, conv2_w, conv2_b, h_flat);
    gate1_kernel<<<1024, 256, 0, stream>>>(h_flat, w_gate1, gt1_out,
                                           rows_list, gate_list, cnt1, imp1, load1);
    moe1_gemm<<<dim3(8, 128), 256, 0, stream>>>(h_flat, W1, b1, rows_list, gate_list,
                                                cnt1, h2quad);
    moe2_head<<<64, 64, 0, stream>>>(h2quad, w_gate2, W2, b2,
                                     gt2_out, logp_out, imp2, load2);
    loss_kernel<<<1, 64, 0, stream>>>(imp1, load1, imp2, load2, loss_out);
}